// Round 2
// baseline (527.343 us; speedup 1.0000x reference)
//
#include <hip/hip_runtime.h>
#include <stdint.h>

#define Bb 8
#define Cc 2048
#define Ee 1024
#define BM 128
#define BN 128
#define BK 32

typedef unsigned short u16;
typedef __attribute__((ext_vector_type(8))) short short8;
typedef __attribute__((ext_vector_type(4))) float f32x4;

__device__ __forceinline__ u16 f2bf(float f){
    unsigned u = __builtin_bit_cast(unsigned, f);
    return (u16)((u + 0x7fffu + ((u >> 16) & 1u)) >> 16);   // RNE, finite inputs
}
__device__ __forceinline__ float bf2f(u16 h){
    return __builtin_bit_cast(float, ((unsigned)h) << 16);
}
__device__ __forceinline__ void gld16(const void* g, void* l){
    __builtin_amdgcn_global_load_lds(
        (const __attribute__((address_space(1))) unsigned int*)g,
        (__attribute__((address_space(3))) unsigned int*)l,
        16, 0, 0);
}

// ---------------- cast fp32 -> bf16 (vectorized) ----------------
__global__ __launch_bounds__(256) void k_cast(const float* __restrict__ s,
                                              u16* __restrict__ d, long n4){
    long i = (long)blockIdx.x * 256 + threadIdx.x;
    const long stride = (long)gridDim.x * 256;
    for (; i < n4; i += stride){
        float4 f = ((const float4*)s)[i];
        ushort4 o = make_ushort4(f2bf(f.x), f2bf(f.y), f2bf(f.z), f2bf(f.w));
        ((ushort4*)d)[i] = o;
    }
}

// ---------------- cast+transpose: x[b][C][E] fp32 -> xT[b][E][C] bf16 ----------------
__global__ __launch_bounds__(256) void k_cast_transpose(const float* __restrict__ src,
                                                        u16* __restrict__ dst){
    __shared__ float tile[32][33];
    const int b = blockIdx.z;
    src += (long)b * Cc * Ee;
    dst += (long)b * Cc * Ee;
    const int c0 = blockIdx.x * 32;   // E-dim block
    const int r0 = blockIdx.y * 32;   // C-dim block
    const int tx = threadIdx.x & 31;
    const int ty = threadIdx.x >> 5;  // 0..7
    #pragma unroll
    for (int p = 0; p < 4; ++p)
        tile[ty + p*8][tx] = src[(long)(r0 + ty + p*8) * Ee + c0 + tx];
    __syncthreads();
    #pragma unroll
    for (int p = 0; p < 4; ++p)
        dst[(long)(c0 + ty + p*8) * Cc + r0 + tx] = f2bf(tile[tx][ty + p*8]);
}

// ---------------- NT GEMM: C[m,n] = scale*sum_k A[m,k]B[n,k] + bias ----------------
// A:[M,K] row-major bf16, B:[N,K] row-major bf16.
// Output: OUT_F32 ? fp32 [M,N] : bf16 ([M,N], or [N,M] if OUT_TRANS)
// BIAS_MODE: 0 none, 1 bias[n], 2 bias[m]
template<int OUT_TRANS, int BIAS_MODE, int OUT_F32>
__global__ __launch_bounds__(256)
void k_gemm_nt(const u16* __restrict__ A, const u16* __restrict__ Bm,
               void* __restrict__ Cout, const float* __restrict__ bias,
               int M, int N, int K, long sA, long sB, long sC, float scale)
{
    const int bz = blockIdx.z;
    A  += (long)bz * sA;
    Bm += (long)bz * sB;
    u16*   Cm = (u16*)Cout + (OUT_F32 ? 0 : (long)bz * sC);
    float* Cf = (float*)Cout + (OUT_F32 ? (long)bz * sC : 0);

    __shared__ u16 As[BM][BK];
    __shared__ u16 Bs[BN][BK];

    const int tid  = threadIdx.x;
    const int lane = tid & 63;
    const int wave = tid >> 6;
    const int wr = wave >> 1, wc = wave & 1;       // 2x2 wave grid, 64x64 per wave
    const int tileM = blockIdx.x * BM;
    const int tileN = blockIdx.y * BN;

    // staging: each thread 16B; LDS offset = tid*16 (linear in lane -> gld_lds safe)
    const int srow = tid >> 2;
    const int sseg = tid & 3;
    const u16* Ag = A  + (long)(tileM + srow) * K + sseg * 8;
    const u16* Bg = Bm + (long)(tileN + srow) * K + sseg * 8;
    u16* lA0 = &As[srow][sseg * 8];
    u16* lA1 = &As[64 + srow][sseg * 8];
    u16* lB0 = &Bs[srow][sseg * 8];
    u16* lB1 = &Bs[64 + srow][sseg * 8];
    const long rowskip = (long)64 * K;

    f32x4 acc[4][4];
    #pragma unroll
    for (int m = 0; m < 4; ++m)
        #pragma unroll
        for (int n = 0; n < 4; ++n)
            acc[m][n] = (f32x4){0.f, 0.f, 0.f, 0.f};

    const int lrow = lane & 15;
    const int lko  = (lane >> 4) * 8;
    const int nk = K / BK;
    for (int kt = 0; kt < nk; ++kt){
        gld16(Ag, lA0);
        gld16(Ag + rowskip, lA1);
        gld16(Bg, lB0);
        gld16(Bg + rowskip, lB1);
        Ag += BK; Bg += BK;
        __syncthreads();                    // drains vmcnt -> staged tile visible
        short8 af[4], bfr[4];
        #pragma unroll
        for (int m = 0; m < 4; ++m)
            af[m] = *(const short8*)&As[wr*64 + m*16 + lrow][lko];
        #pragma unroll
        for (int n = 0; n < 4; ++n)
            bfr[n] = *(const short8*)&Bs[wc*64 + n*16 + lrow][lko];
        #pragma unroll
        for (int m = 0; m < 4; ++m)
            #pragma unroll
            for (int n = 0; n < 4; ++n)
                acc[m][n] = __builtin_amdgcn_mfma_f32_16x16x32_bf16(af[m], bfr[n], acc[m][n], 0, 0, 0);
        __syncthreads();                    // all waves done reading before next stage
    }

    // epilogue: C/D layout col = lane&15, row = (lane>>4)*4 + j   [verified m89/m91]
    const int crow0 = tileM + wr*64 + (lane >> 4) * 4;
    const int ccol0 = tileN + wc*64 + (lane & 15);
    #pragma unroll
    for (int m = 0; m < 4; ++m){
        const int r0 = crow0 + m * 16;
        #pragma unroll
        for (int n = 0; n < 4; ++n){
            const int c = ccol0 + n * 16;
            f32x4 v = acc[m][n];
            float vv[4];
            #pragma unroll
            for (int j = 0; j < 4; ++j){
                float val = v[j] * scale;
                if (BIAS_MODE == 1) val += bias[c];
                if (BIAS_MODE == 2) val += bias[r0 + j];
                vv[j] = val;
            }
            if (OUT_F32){
                #pragma unroll
                for (int j = 0; j < 4; ++j)
                    Cf[(long)(r0 + j) * N + c] = vv[j];
            } else if (OUT_TRANS){
                // store C^T: dst[c][r0..r0+3], leading dim = M (rows are contiguous k)
                ushort4 o = make_ushort4(f2bf(vv[0]), f2bf(vv[1]), f2bf(vv[2]), f2bf(vv[3]));
                *(ushort4*)&Cm[(long)c * M + r0] = o;
            } else {
                #pragma unroll
                for (int j = 0; j < 4; ++j)
                    Cm[(long)(r0 + j) * N + c] = f2bf(vv[j]);
            }
        }
    }
}

// ---------------- row softmax, in-place on bf16 [rows x 2048] ----------------
__global__ __launch_bounds__(256) void k_softmax(u16* __restrict__ P){
    u16* p = P + (long)blockIdx.x * Cc;
    const int tid = threadIdx.x;
    short8 raw = *(const short8*)(p + tid * 8);
    float v[8];
    float mx = -3.0e38f;
    #pragma unroll
    for (int i = 0; i < 8; ++i){ v[i] = bf2f((u16)raw[i]); mx = fmaxf(mx, v[i]); }
    #pragma unroll
    for (int o = 32; o > 0; o >>= 1) mx = fmaxf(mx, __shfl_xor(mx, o));
    __shared__ float redm[4];
    if ((tid & 63) == 0) redm[tid >> 6] = mx;
    __syncthreads();
    mx = fmaxf(fmaxf(redm[0], redm[1]), fmaxf(redm[2], redm[3]));
    float s = 0.f;
    #pragma unroll
    for (int i = 0; i < 8; ++i){ v[i] = __expf(v[i] - mx); s += v[i]; }
    #pragma unroll
    for (int o = 32; o > 0; o >>= 1) s += __shfl_xor(s, o);
    __shared__ float reds[4];
    if ((tid & 63) == 0) reds[tid >> 6] = s;
    __syncthreads();
    s = reds[0] + reds[1] + reds[2] + reds[3];
    const float inv = 1.f / s;
    short8 o8;
    #pragma unroll
    for (int i = 0; i < 8; ++i) o8[i] = (short)f2bf(v[i] * inv);
    *(short8*)(p + tid * 8) = o8;
}

static inline int cast_grid(long n4){
    long g = (n4 + 255) / 256;
    return (int)(g > 2048 ? 2048 : g);
}

extern "C" void kernel_launch(void* const* d_in, const int* in_sizes, int n_in,
                              void* d_out, int out_size, void* d_ws, size_t ws_size,
                              hipStream_t stream)
{
    const float* x     = (const float*)d_in[0];
    const float* fc_w  = (const float*)d_in[1];
    const float* fc_b  = (const float*)d_in[2];
    const float* altw  = (const float*)d_in[3];
    const float* altb  = (const float*)d_in[4];
    const float* vfc_w = (const float*)d_in[5];
    const float* vfc_b = (const float*)d_in[6];
    float* out = (float*)d_out;   // reference output is fp32

    char* ws = (char*)d_ws;
    const size_t nBCE = (size_t)Bb * Cc * Ee;            // 16,777,216 elements
    // byte layout (bf16 = 2B/el):
    u16* xb   = (u16*)(ws);                              // [B][C][E]   33.5MB
    u16* xbT  = (u16*)(ws + 2 * nBCE);                   // [B][E][C]   33.5MB
    u16* P    = (u16*)(ws);                              // [B][C][C]   67MB  (aliases xb+xbT, both dead by then)
    u16* y    = (u16*)(ws + 4 * nBCE);                   // [B][C][E]
    u16* z    = (u16*)(ws + 6 * nBCE);                   // [B][C][E]   (z[b][k][e] = yx[b,e,k])
    u16* vxT  = (u16*)(ws + 8 * nBCE);                   // [B][E][C]
    u16* fcwb = (u16*)(ws + 10 * nBCE);                  // [E][E]
    u16* vfwb = fcwb + (size_t)Ee * Ee;
    u16* awb  = vfwb + (size_t)Ee * Ee;                  // [C][C]
    // total ~180.4 MB

    // 1) casts
    k_cast<<<cast_grid((long)nBCE / 4), 256, 0, stream>>>(x, xb, (long)nBCE / 4);
    k_cast<<<cast_grid((long)Ee * Ee / 4), 256, 0, stream>>>(fc_w, fcwb, (long)Ee * Ee / 4);
    k_cast<<<cast_grid((long)Ee * Ee / 4), 256, 0, stream>>>(vfc_w, vfwb, (long)Ee * Ee / 4);
    k_cast<<<cast_grid((long)Cc * Cc / 4), 256, 0, stream>>>(altw, awb, (long)Cc * Cc / 4);
    k_cast_transpose<<<dim3(Ee / 32, Cc / 32, Bb), 256, 0, stream>>>(x, xbT);

    const long sBCE = (long)Cc * Ee;
    const long sBCC = (long)Cc * Cc;
    dim3 blk(256);

    // 2) y[b][c][f] = sum_e xb[c,e] fcw[f,e] + fc_b[f]
    k_gemm_nt<0, 1, 0><<<dim3(Cc / BM, Ee / BN, Bb), blk, 0, stream>>>(
        xb, fcwb, y, fc_b, Cc, Ee, Ee, sBCE, 0, sBCE, 1.f);

    // 3) vxT[b][f][k] = sum_e xb[k,e] vfcw[f,e] + vfc_b[f]   (transposed store)
    k_gemm_nt<1, 1, 0><<<dim3(Cc / BM, Ee / BN, Bb), blk, 0, stream>>>(
        xb, vfwb, vxT, vfc_b, Cc, Ee, Ee, sBCE, 0, sBCE, 1.f);

    // 4) z[b][k][e] = sum_c altw[k,c] xT[e,c] + alt_b[k]   (bias per m)
    k_gemm_nt<0, 2, 0><<<dim3(Cc / BM, Ee / BN, Bb), blk, 0, stream>>>(
        awb, xbT, z, altb, Cc, Ee, Cc, 0, sBCE, sBCE, 1.f);

    // 5) P[b][c][k] = (1/sqrt(C)) * sum_e y[c,e] z[k,e]
    k_gemm_nt<0, 0, 0><<<dim3(Cc / BM, Cc / BN, Bb), blk, 0, stream>>>(
        y, z, P, nullptr, Cc, Cc, Ee, sBCE, sBCE, sBCC, 0.022097086912079608f);

    // 6) softmax rows of P (in place)
    k_softmax<<<Bb * Cc, 256, 0, stream>>>(P);

    // 7) out[b][c][e] = sum_k P[c,k] vxT[e,k]  -> fp32 d_out
    k_gemm_nt<0, 0, 1><<<dim3(Cc / BM, Ee / BN, Bb), blk, 0, stream>>>(
        P, vxT, out, nullptr, Cc, Ee, Cc, sBCC, sBCE, sBCE, 1.f);
}

// Round 3
// 368.254 us; speedup vs baseline: 1.4320x; 1.4320x over previous
//
#include <hip/hip_runtime.h>
#include <stdint.h>

#define Bb 8
#define Cc 2048
#define Ee 1024

typedef unsigned short u16;
typedef __attribute__((ext_vector_type(8))) short short8;
typedef __attribute__((ext_vector_type(4))) float f32x4;

__device__ __forceinline__ u16 f2bf(float f){
    unsigned u = __builtin_bit_cast(unsigned, f);
    return (u16)((u + 0x7fffu + ((u >> 16) & 1u)) >> 16);   // RNE, finite inputs
}
__device__ __forceinline__ float bf2f(u16 h){
    return __builtin_bit_cast(float, ((unsigned)h) << 16);
}
__device__ __forceinline__ void gld16(const void* g, void* l){
    __builtin_amdgcn_global_load_lds(
        (const __attribute__((address_space(1))) unsigned int*)g,
        (__attribute__((address_space(3))) unsigned int*)l,
        16, 0, 0);
}
#define MFMA(a,b,c) __builtin_amdgcn_mfma_f32_16x16x32_bf16((a),(b),(c),0,0,0)
#define SBAR()  __builtin_amdgcn_s_barrier()
#define SCHED0() __builtin_amdgcn_sched_barrier(0)
#define LGKM0() asm volatile("s_waitcnt lgkmcnt(0)" ::: "memory")

// ---------------- cast fp32 -> bf16 (vectorized) ----------------
__global__ __launch_bounds__(256) void k_cast(const float* __restrict__ s,
                                              u16* __restrict__ d, long n4){
    long i = (long)blockIdx.x * 256 + threadIdx.x;
    const long stride = (long)gridDim.x * 256;
    for (; i < n4; i += stride){
        float4 f = ((const float4*)s)[i];
        ushort4 o = make_ushort4(f2bf(f.x), f2bf(f.y), f2bf(f.z), f2bf(f.w));
        ((ushort4*)d)[i] = o;
    }
}

// ---------------- cast+transpose: x[b][C][E] fp32 -> xT[b][E][C] bf16 ----------------
__global__ __launch_bounds__(256) void k_cast_transpose(const float* __restrict__ src,
                                                        u16* __restrict__ dst){
    __shared__ float tile[32][33];
    const int b = blockIdx.z;
    src += (long)b * Cc * Ee;
    dst += (long)b * Cc * Ee;
    const int c0 = blockIdx.x * 32;   // E-dim block
    const int r0 = blockIdx.y * 32;   // C-dim block
    const int tx = threadIdx.x & 31;
    const int ty = threadIdx.x >> 5;  // 0..7
    #pragma unroll
    for (int p = 0; p < 4; ++p)
        tile[ty + p*8][tx] = src[(long)(r0 + ty + p*8) * Ee + c0 + tx];
    __syncthreads();
    #pragma unroll
    for (int p = 0; p < 4; ++p)
        dst[(long)(c0 + ty + p*8) * Cc + r0 + tx] = f2bf(tile[tx][ty + p*8]);
}

// =============== 256x256 8-phase NT GEMM ===============
// C[m,n] = scale * sum_k A[m,k]*B[n,k] (+bias); A:[M,K], B:[N,K] bf16 row-major.
// 512 thr = 8 waves (2M x 4N); BK=64; LDS 128KiB double-buffered;
// per-phase: ds_read frags | stage 2x8KiB units | barrier | lgkm0 | 16 MFMA | barrier.
// counted vmcnt: p2 -> vmcnt(4), p4 -> vmcnt(2) (before end barrier).
// LDS swizzle: 16B-chunk c stored/read at c ^ (row&7)  (pre-swizzled global src).
// BIAS_MODE: 0 none, 1 bias[col], 2 bias[row].  OUT_F32: fp32 out else bf16.
template<int BIAS_MODE, int OUT_F32>
__global__ __launch_bounds__(512, 2)
void k_gemm256(const u16* __restrict__ A, const u16* __restrict__ Bm,
               void* __restrict__ Cout, const float* __restrict__ bias,
               int N, int K, long sA, long sB, long sC, float scale)
{
    __shared__ __attribute__((aligned(16))) char smem[131072];
    const int bz = blockIdx.z;
    A  += (long)bz * sA;
    Bm += (long)bz * sB;
    u16*   Cm = (u16*)Cout + (OUT_F32 ? 0 : (long)bz * sC);
    float* Cf = (float*)Cout + (OUT_F32 ? (long)bz * sC : 0);

    const int tid  = threadIdx.x;
    const int lane = tid & 63;
    const int wave = tid >> 6;
    const int wr = wave >> 2;          // 0..1  (M half)
    const int wc = wave & 3;           // 0..3  (N quarter)
    const int tileM = blockIdx.x * 256;
    const int tileN = blockIdx.y * 256;

    // ---- staging constants: unit = 64 rows x 64 cols (8KiB) = 1 gld16/thread
    const int srow   = tid >> 3;                 // 0..63 (row within unit)
    const int schunk = (tid & 7) ^ (srow & 7);   // pre-swizzled 16B chunk
    const u16* Ag = A  + (long)(tileM + srow) * K + schunk * 8;
    const u16* Bg = Bm + (long)(tileN + srow) * K + schunk * 8;
    const long uK = (long)64 * K;                // global stride per unit
    const int  ldst = tid * 16;                  // linear LDS dest (wave-uniform + lane*16)

    // ---- ds_read constants (swizzled chunk)
    const int lrow = lane & 15;
    const int lk   = lane >> 4;                  // 0..3
    const int sw   = lrow & 7;
    const int cs0  = ((0 + lk) ^ sw) * 16;       // kk=0 chunk byte
    const int cs1  = ((4 + lk) ^ sw) * 16;       // kk=1 chunk byte
    const int arow0 = (wr*128 + lrow) * 128;             // A row byte off in tile
    const int brow0 = 32768 + (wc*64 + lrow) * 128;      // B row byte off in tile

    f32x4 acc[8][4];
    #pragma unroll
    for (int m = 0; m < 8; ++m)
        #pragma unroll
        for (int n = 0; n < 4; ++n)
            acc[m][n] = (f32x4){0.f,0.f,0.f,0.f};

    char* sm = smem;
    // ---- prologue: stage tile 0 into buf0, full drain (one-time)
    #pragma unroll
    for (int u = 0; u < 4; ++u) gld16(Bg + u*uK, sm + 32768 + u*8192 + ldst);
    #pragma unroll
    for (int u = 0; u < 4; ++u) gld16(Ag + u*uK, sm + u*8192 + ldst);
    __syncthreads();

    const int NT = K >> 6;
    short8 aF[4][2], bF[2][2];

    for (int t = 0; t < NT; ++t){
        const bool pref = (t + 1) < NT;
        char* cbuf = sm + ((t & 1) << 16);
        char* nbuf = sm + (((t + 1) & 1) << 16);
        const u16* Agt = Ag + (t + 1) * 64;
        const u16* Bgt = Bg + (t + 1) * 64;

        // ================= phase 1: quadrant (mh0, nh0) =================
        #pragma unroll
        for (int m = 0; m < 4; ++m){
            aF[m][0] = *(const short8*)(cbuf + arow0 + m*2048 + cs0);
            aF[m][1] = *(const short8*)(cbuf + arow0 + m*2048 + cs1);
        }
        #pragma unroll
        for (int n = 0; n < 2; ++n){
            bF[n][0] = *(const short8*)(cbuf + brow0 + n*2048 + cs0);
            bF[n][1] = *(const short8*)(cbuf + brow0 + n*2048 + cs1);
        }
        if (pref){ gld16(Bgt + 0*uK, nbuf + 32768 + 0*8192 + ldst);
                   gld16(Bgt + 1*uK, nbuf + 32768 + 1*8192 + ldst); }
        SCHED0(); SBAR(); LGKM0(); SCHED0();
        __builtin_amdgcn_s_setprio(1);
        #pragma unroll
        for (int m = 0; m < 4; ++m)
            #pragma unroll
            for (int n = 0; n < 2; ++n){
                acc[m][n] = MFMA(aF[m][0], bF[n][0], acc[m][n]);
                acc[m][n] = MFMA(aF[m][1], bF[n][1], acc[m][n]);
            }
        __builtin_amdgcn_s_setprio(0);
        SBAR(); SCHED0();

        // ================= phase 2: (mh0, nh1) — new B =================
        #pragma unroll
        for (int n = 0; n < 2; ++n){
            bF[n][0] = *(const short8*)(cbuf + brow0 + (n+2)*2048 + cs0);
            bF[n][1] = *(const short8*)(cbuf + brow0 + (n+2)*2048 + cs1);
        }
        if (pref){ gld16(Bgt + 2*uK, nbuf + 32768 + 2*8192 + ldst);
                   gld16(Bgt + 3*uK, nbuf + 32768 + 3*8192 + ldst); }
        SCHED0(); SBAR(); LGKM0(); SCHED0();
        __builtin_amdgcn_s_setprio(1);
        #pragma unroll
        for (int m = 0; m < 4; ++m)
            #pragma unroll
            for (int n = 0; n < 2; ++n){
                acc[m][n+2] = MFMA(aF[m][0], bF[n][0], acc[m][n+2]);
                acc[m][n+2] = MFMA(aF[m][1], bF[n][1], acc[m][n+2]);
            }
        __builtin_amdgcn_s_setprio(0);
        if (pref){ asm volatile("s_waitcnt vmcnt(4)" ::: "memory"); }
        else     { asm volatile("s_waitcnt vmcnt(0)" ::: "memory"); }
        SBAR(); SCHED0();

        // ================= phase 3: (mh1, nh1) — new A =================
        #pragma unroll
        for (int m = 0; m < 4; ++m){
            aF[m][0] = *(const short8*)(cbuf + arow0 + (m+4)*2048 + cs0);
            aF[m][1] = *(const short8*)(cbuf + arow0 + (m+4)*2048 + cs1);
        }
        if (pref){ gld16(Agt + 0*uK, nbuf + 0*8192 + ldst);
                   gld16(Agt + 2*uK, nbuf + 2*8192 + ldst); }
        SCHED0(); SBAR(); LGKM0(); SCHED0();
        __builtin_amdgcn_s_setprio(1);
        #pragma unroll
        for (int m = 0; m < 4; ++m)
            #pragma unroll
            for (int n = 0; n < 2; ++n){
                acc[m+4][n+2] = MFMA(aF[m][0], bF[n][0], acc[m+4][n+2]);
                acc[m+4][n+2] = MFMA(aF[m][1], bF[n][1], acc[m+4][n+2]);
            }
        __builtin_amdgcn_s_setprio(0);
        SBAR(); SCHED0();

        // ================= phase 4: (mh1, nh0) — re-read B =================
        #pragma unroll
        for (int n = 0; n < 2; ++n){
            bF[n][0] = *(const short8*)(cbuf + brow0 + n*2048 + cs0);
            bF[n][1] = *(const short8*)(cbuf + brow0 + n*2048 + cs1);
        }
        if (pref){ gld16(Agt + 1*uK, nbuf + 1*8192 + ldst);
                   gld16(Agt + 3*uK, nbuf + 3*8192 + ldst); }
        SCHED0(); SBAR(); LGKM0(); SCHED0();
        __builtin_amdgcn_s_setprio(1);
        #pragma unroll
        for (int m = 0; m < 4; ++m)
            #pragma unroll
            for (int n = 0; n < 2; ++n){
                acc[m+4][n] = MFMA(aF[m][0], bF[n][0], acc[m+4][n]);
                acc[m+4][n] = MFMA(aF[m][1], bF[n][1], acc[m+4][n]);
            }
        __builtin_amdgcn_s_setprio(0);
        asm volatile("s_waitcnt vmcnt(2)" ::: "memory");
        SBAR(); SCHED0();
    }

    // ---- epilogue: C/D layout col=lane&15, row=(lane>>4)*4+j
    const int r0base = tileM + wr*128 + lk*4;
    const int cbase  = tileN + wc*64 + lrow;
    #pragma unroll
    for (int m = 0; m < 8; ++m){
        const int r0 = r0base + m*16;
        #pragma unroll
        for (int n = 0; n < 4; ++n){
            const int c = cbase + n*16;
            f32x4 v = acc[m][n];
            #pragma unroll
            for (int j = 0; j < 4; ++j){
                float val = v[j] * scale;
                if (BIAS_MODE == 1) val += bias[c];
                if (BIAS_MODE == 2) val += bias[r0 + j];
                if (OUT_F32) Cf[(long)(r0 + j) * N + c] = val;
                else         Cm[(long)(r0 + j) * N + c] = f2bf(val);
            }
        }
    }
}

// ---------------- row softmax, in-place on bf16 [rows x 2048] ----------------
__global__ __launch_bounds__(256) void k_softmax(u16* __restrict__ P){
    u16* p = P + (long)blockIdx.x * Cc;
    const int tid = threadIdx.x;
    short8 raw = *(const short8*)(p + tid * 8);
    float v[8];
    float mx = -3.0e38f;
    #pragma unroll
    for (int i = 0; i < 8; ++i){ v[i] = bf2f((u16)raw[i]); mx = fmaxf(mx, v[i]); }
    #pragma unroll
    for (int o = 32; o > 0; o >>= 1) mx = fmaxf(mx, __shfl_xor(mx, o));
    __shared__ float redm[4];
    if ((tid & 63) == 0) redm[tid >> 6] = mx;
    __syncthreads();
    mx = fmaxf(fmaxf(redm[0], redm[1]), fmaxf(redm[2], redm[3]));
    float s = 0.f;
    #pragma unroll
    for (int i = 0; i < 8; ++i){ v[i] = __expf(v[i] - mx); s += v[i]; }
    #pragma unroll
    for (int o = 32; o > 0; o >>= 1) s += __shfl_xor(s, o);
    __shared__ float reds[4];
    if ((tid & 63) == 0) reds[tid >> 6] = s;
    __syncthreads();
    s = reds[0] + reds[1] + reds[2] + reds[3];
    const float inv = 1.f / s;
    short8 o8;
    #pragma unroll
    for (int i = 0; i < 8; ++i) o8[i] = (short)f2bf(v[i] * inv);
    *(short8*)(p + tid * 8) = o8;
}

static inline int cast_grid(long n4){
    long g = (n4 + 255) / 256;
    return (int)(g > 2048 ? 2048 : g);
}

extern "C" void kernel_launch(void* const* d_in, const int* in_sizes, int n_in,
                              void* d_out, int out_size, void* d_ws, size_t ws_size,
                              hipStream_t stream)
{
    const float* x     = (const float*)d_in[0];
    const float* fc_w  = (const float*)d_in[1];
    const float* fc_b  = (const float*)d_in[2];
    const float* altw  = (const float*)d_in[3];
    const float* altb  = (const float*)d_in[4];
    const float* vfc_w = (const float*)d_in[5];
    const float* vfc_b = (const float*)d_in[6];
    float* out = (float*)d_out;   // reference output is fp32

    char* ws = (char*)d_ws;
    const size_t nBCE = (size_t)Bb * Cc * Ee;            // 16,777,216 elements
    u16* xb   = (u16*)(ws);                              // [B][C][E]
    u16* xbT  = (u16*)(ws + 2 * nBCE);                   // [B][E][C]
    u16* P    = (u16*)(ws);                              // [B][C][C] (aliases xb+xbT, dead by then)
    u16* y    = (u16*)(ws + 4 * nBCE);                   // [B][C][E]
    u16* z    = (u16*)(ws + 6 * nBCE);                   // [B][C][E]   z[b][k][e] = yx[b,e,k]
    u16* vxT  = (u16*)(ws + 8 * nBCE);                   // [B][E][C]   vxT[b][f][k] = vx[b,k,f]
    u16* fcwb = (u16*)(ws + 10 * nBCE);                  // [E][E]
    u16* vfwb = fcwb + (size_t)Ee * Ee;
    u16* awb  = vfwb + (size_t)Ee * Ee;                  // [C][C]

    // 1) casts
    k_cast<<<cast_grid((long)nBCE / 4), 256, 0, stream>>>(x, xb, (long)nBCE / 4);
    k_cast<<<cast_grid((long)Ee * Ee / 4), 256, 0, stream>>>(fc_w, fcwb, (long)Ee * Ee / 4);
    k_cast<<<cast_grid((long)Ee * Ee / 4), 256, 0, stream>>>(vfc_w, vfwb, (long)Ee * Ee / 4);
    k_cast<<<cast_grid((long)Cc * Cc / 4), 256, 0, stream>>>(altw, awb, (long)Cc * Cc / 4);
    k_cast_transpose<<<dim3(Ee / 32, Cc / 32, Bb), 256, 0, stream>>>(x, xbT);

    const long sBCE = (long)Cc * Ee;
    const long sBCC = (long)Cc * Cc;
    dim3 blk(512);

    // 2) y[b][c][f] = sum_e xb[c,e] fcw[f,e] + fc_b[f]        M=C,N=E,K=E
    k_gemm256<1, 0><<<dim3(Cc/256, Ee/256, Bb), blk, 0, stream>>>(
        xb, fcwb, y, fc_b, Ee, Ee, sBCE, 0, sBCE, 1.f);

    // 3) vxT[b][f][k] = sum_e vfcw[f,e] xb[k,e] + vfc_b[f]    M=E,N=C,K=E (bias per row)
    k_gemm256<2, 0><<<dim3(Ee/256, Cc/256, Bb), blk, 0, stream>>>(
        vfwb, xb, vxT, vfc_b, Cc, Ee, 0, sBCE, sBCE, 1.f);

    // 4) z[b][k][e] = sum_c altw[k,c] xT[e,c] + alt_b[k]      M=C,N=E,K=C (bias per row)
    k_gemm256<2, 0><<<dim3(Cc/256, Ee/256, Bb), blk, 0, stream>>>(
        awb, xbT, z, altb, Ee, Cc, 0, sBCE, sBCE, 1.f);

    // 5) P[b][c][k] = (1/sqrt(C)) * sum_e y[c,e] z[k,e]       M=C,N=C,K=E
    k_gemm256<0, 0><<<dim3(Cc/256, Cc/256, Bb), blk, 0, stream>>>(
        y, z, P, nullptr, Cc, Ee, sBCE, sBCE, sBCC, 0.022097086912079608f);

    // 6) softmax rows of P (in place)
    k_softmax<<<Bb * Cc, 256, 0, stream>>>(P);

    // 7) out[b][c][e] = sum_k P[c,k] vxT[e,k] -> fp32         M=C,N=E,K=C
    k_gemm256<0, 1><<<dim3(Cc/256, Ee/256, Bb), blk, 0, stream>>>(
        P, vxT, out, nullptr, Ee, Cc, sBCC, sBCE, sBCE, 1.f);
}

// Round 4
// 353.480 us; speedup vs baseline: 1.4919x; 1.0418x over previous
//
#include <hip/hip_runtime.h>
#include <stdint.h>

#define Bb 8
#define Cc 2048
#define Ee 1024

typedef unsigned short u16;
typedef __attribute__((ext_vector_type(8))) short short8;
typedef __attribute__((ext_vector_type(4))) float f32x4;

__device__ __forceinline__ u16 f2bf(float f){
    unsigned u = __builtin_bit_cast(unsigned, f);
    return (u16)((u + 0x7fffu + ((u >> 16) & 1u)) >> 16);   // RNE, finite inputs
}
__device__ __forceinline__ float bf2f(u16 h){
    return __builtin_bit_cast(float, ((unsigned)h) << 16);
}
__device__ __forceinline__ void gld16(const void* g, void* l){
    __builtin_amdgcn_global_load_lds(
        (const __attribute__((address_space(1))) unsigned int*)g,
        (__attribute__((address_space(3))) unsigned int*)l,
        16, 0, 0);
}
#define MFMA(a,b,c) __builtin_amdgcn_mfma_f32_16x16x32_bf16((a),(b),(c),0,0,0)
#define SBAR()  __builtin_amdgcn_s_barrier()
#define SCHED0() __builtin_amdgcn_sched_barrier(0)
#define LGKM0() asm volatile("s_waitcnt lgkmcnt(0)" ::: "memory")
#define VMCNT2() asm volatile("s_waitcnt vmcnt(2)" ::: "memory")
#define VMCNT0() asm volatile("s_waitcnt vmcnt(0)" ::: "memory")

// ---------------- cast fp32 -> bf16 (vectorized) ----------------
__global__ __launch_bounds__(256) void k_cast(const float* __restrict__ s,
                                              u16* __restrict__ d, long n4){
    long i = (long)blockIdx.x * 256 + threadIdx.x;
    const long stride = (long)gridDim.x * 256;
    for (; i < n4; i += stride){
        float4 f = ((const float4*)s)[i];
        ushort4 o = make_ushort4(f2bf(f.x), f2bf(f.y), f2bf(f.z), f2bf(f.w));
        ((ushort4*)d)[i] = o;
    }
}

// ------ fused: x fp32 -> xb bf16 (straight) + xbT bf16 (transposed) ------
__global__ __launch_bounds__(256) void k_cast_xt(const float* __restrict__ src,
                                                 u16* __restrict__ xb,
                                                 u16* __restrict__ xbT){
    __shared__ float tile[32][33];
    const int b = blockIdx.z;
    src += (long)b * Cc * Ee;
    xb  += (long)b * Cc * Ee;
    xbT += (long)b * Cc * Ee;
    const int c0 = blockIdx.x * 32;   // E-dim block
    const int r0 = blockIdx.y * 32;   // C-dim block
    const int tx = threadIdx.x & 31;
    const int ty = threadIdx.x >> 5;  // 0..7
    #pragma unroll
    for (int p = 0; p < 4; ++p){
        float v = src[(long)(r0 + ty + p*8) * Ee + c0 + tx];
        tile[ty + p*8][tx] = v;
        xb[(long)(r0 + ty + p*8) * Ee + c0 + tx] = f2bf(v);
    }
    __syncthreads();
    #pragma unroll
    for (int p = 0; p < 4; ++p)
        xbT[(long)(c0 + ty + p*8) * Cc + r0 + tx] = f2bf(tile[tx][ty + p*8]);
}

// =============== 256x256 8-phase NT GEMM (kk-split, 24 ds_read/tile) ===============
// C[m,n] = scale * sum_k A[m,k]*B[n,k] (+bias); A:[M,K], B:[N,K] bf16 row-major.
// 512 thr = 8 waves (2M x 4N); BK=64; LDS 128KiB double-buffered.
// Phase walk per K-tile: p1 (m0-3,all n, kk0) reads 8; p2 (m4-7, kk0) reads 4;
//                        p3 (m0-3, kk1) reads 8; p4 (m4-7, kk1) reads 4.
// Staging (2 units/phase): p1: A0,A2 | p2: B0,B1 | p3: B2,B3 | p4: A1,A3.
// vmcnt(2) at p1-end (A1,A3 of cur tile done) and p4-end (A0,A2,B0-3 of next done).
// LDS swizzle: 16B-chunk c at c ^ (row&7); pre-swizzled global source.
// BIAS_MODE: 0 none, 1 bias[col], 2 bias[row].  OUT_F32: fp32 out else bf16.
template<int BIAS_MODE, int OUT_F32>
__global__ __launch_bounds__(512, 2)
void k_gemm256(const u16* __restrict__ A, const u16* __restrict__ Bm,
               void* __restrict__ Cout, const float* __restrict__ bias,
               int N, int K, long sA, long sB, long sC, float scale)
{
    __shared__ __attribute__((aligned(16))) char smem[131072];

    // ---- bijective XCD swizzle (nwg % 8 == 0 for all launches here)
    const int gx = gridDim.x, gy = gridDim.y;
    const int nwg = gx * gy * gridDim.z;
    const int lin = blockIdx.x + gx * (blockIdx.y + gy * blockIdx.z);
    const int swz = (lin & 7) * (nwg >> 3) + (lin >> 3);
    const int bx = swz % gx;
    const int tmp = swz / gx;
    const int by = tmp % gy;
    const int bz = tmp / gy;

    A  += (long)bz * sA;
    Bm += (long)bz * sB;
    u16*   Cm = (u16*)Cout + (OUT_F32 ? 0 : (long)bz * sC);
    float* Cf = (float*)Cout + (OUT_F32 ? (long)bz * sC : 0);

    const int tid  = threadIdx.x;
    const int lane = tid & 63;
    const int wave = tid >> 6;
    const int wr = wave >> 2;          // 0..1  (M half)
    const int wc = wave & 3;           // 0..3  (N quarter)
    const int tileM = bx * 256;
    const int tileN = by * 256;

    // ---- staging constants: unit = 64 rows x 64 cols (8KiB) = 1 gld16/thread
    const int srow   = tid >> 3;                 // 0..63 (row within unit)
    const int schunk = (tid & 7) ^ (srow & 7);   // pre-swizzled 16B chunk
    const u16* Ag = A  + (long)(tileM + srow) * K + schunk * 8;
    const u16* Bg = Bm + (long)(tileN + srow) * K + schunk * 8;
    const long uK = (long)64 * K;                // global stride per unit
    const int  ldst = tid * 16;                  // linear LDS dest

    // ---- ds_read constants (swizzled chunk)
    const int lrow = lane & 15;
    const int lk   = lane >> 4;                  // 0..3
    const int sw   = lrow & 7;
    const int cs0  = ((0 + lk) ^ sw) * 16;       // kk=0 chunk byte
    const int cs1  = ((4 + lk) ^ sw) * 16;       // kk=1 chunk byte
    const int arow0 = (wr*128 + lrow) * 128;             // A row byte off in tile
    const int brow0 = 32768 + (wc*64 + lrow) * 128;      // B row byte off in tile

    f32x4 acc[8][4];
    #pragma unroll
    for (int m = 0; m < 8; ++m)
        #pragma unroll
        for (int n = 0; n < 4; ++n)
            acc[m][n] = (f32x4){0.f,0.f,0.f,0.f};

    char* sm = smem;
    // ---- prologue: stage tile 0 into buf0, full drain (one-time)
    #pragma unroll
    for (int u = 0; u < 4; ++u) gld16(Bg + u*uK, sm + 32768 + u*8192 + ldst);
    #pragma unroll
    for (int u = 0; u < 4; ++u) gld16(Ag + u*uK, sm + u*8192 + ldst);
    __syncthreads();

    const int NT = K >> 6;
    short8 aF[4], bF[4];

    for (int t = 0; t < NT; ++t){
        const bool pref = (t + 1) < NT;
        char* cbuf = sm + ((t & 1) << 16);
        char* nbuf = sm + (((t + 1) & 1) << 16);
        const u16* Agt = Ag + (long)(t + 1) * 64;
        const u16* Bgt = Bg + (long)(t + 1) * 64;

        // ===== p1: (m0-3, all n, kk0) — 8 reads; stage A0,A2 =====
        #pragma unroll
        for (int m = 0; m < 4; ++m) aF[m] = *(const short8*)(cbuf + arow0 + m*2048 + cs0);
        #pragma unroll
        for (int n = 0; n < 4; ++n) bF[n] = *(const short8*)(cbuf + brow0 + n*2048 + cs0);
        if (pref){ gld16(Agt + 0*uK, nbuf + 0*8192 + ldst);
                   gld16(Agt + 2*uK, nbuf + 2*8192 + ldst); }
        SCHED0(); SBAR(); LGKM0(); SCHED0();
        __builtin_amdgcn_s_setprio(1);
        #pragma unroll
        for (int m = 0; m < 4; ++m)
            #pragma unroll
            for (int n = 0; n < 4; ++n)
                acc[m][n] = MFMA(aF[m], bF[n], acc[m][n]);
        __builtin_amdgcn_s_setprio(0);
        if (pref){ VMCNT2(); } else { VMCNT0(); }   // A1,A3 of cur tile landed
        SBAR(); SCHED0();

        // ===== p2: (m4-7, kk0) — 4 reads; stage B0,B1 =====
        #pragma unroll
        for (int m = 0; m < 4; ++m) aF[m] = *(const short8*)(cbuf + arow0 + (m+4)*2048 + cs0);
        if (pref){ gld16(Bgt + 0*uK, nbuf + 32768 + 0*8192 + ldst);
                   gld16(Bgt + 1*uK, nbuf + 32768 + 1*8192 + ldst); }
        SCHED0(); SBAR(); LGKM0(); SCHED0();
        __builtin_amdgcn_s_setprio(1);
        #pragma unroll
        for (int m = 0; m < 4; ++m)
            #pragma unroll
            for (int n = 0; n < 4; ++n)
                acc[m+4][n] = MFMA(aF[m], bF[n], acc[m+4][n]);
        __builtin_amdgcn_s_setprio(0);
        SBAR(); SCHED0();

        // ===== p3: (m0-3, kk1) — 8 reads; stage B2,B3 =====
        #pragma unroll
        for (int m = 0; m < 4; ++m) aF[m] = *(const short8*)(cbuf + arow0 + m*2048 + cs1);
        #pragma unroll
        for (int n = 0; n < 4; ++n) bF[n] = *(const short8*)(cbuf + brow0 + n*2048 + cs1);
        if (pref){ gld16(Bgt + 2*uK, nbuf + 32768 + 2*8192 + ldst);
                   gld16(Bgt + 3*uK, nbuf + 32768 + 3*8192 + ldst); }
        SCHED0(); SBAR(); LGKM0(); SCHED0();
        __builtin_amdgcn_s_setprio(1);
        #pragma unroll
        for (int m = 0; m < 4; ++m)
            #pragma unroll
            for (int n = 0; n < 4; ++n)
                acc[m][n] = MFMA(aF[m], bF[n], acc[m][n]);
        __builtin_amdgcn_s_setprio(0);
        SBAR(); SCHED0();

        // ===== p4: (m4-7, kk1) — 4 reads; stage A1,A3 =====
        #pragma unroll
        for (int m = 0; m < 4; ++m) aF[m] = *(const short8*)(cbuf + arow0 + (m+4)*2048 + cs1);
        if (pref){ gld16(Agt + 1*uK, nbuf + 1*8192 + ldst);
                   gld16(Agt + 3*uK, nbuf + 3*8192 + ldst); }
        SCHED0(); SBAR(); LGKM0(); SCHED0();
        __builtin_amdgcn_s_setprio(1);
        #pragma unroll
        for (int m = 0; m < 4; ++m)
            #pragma unroll
            for (int n = 0; n < 4; ++n)
                acc[m+4][n] = MFMA(aF[m], bF[n], acc[m+4][n]);
        __builtin_amdgcn_s_setprio(0);
        if (pref){ VMCNT2(); }                      // A0,A2,B0-3 of next tile landed
        SBAR(); SCHED0();
    }

    // ---- epilogue: C/D layout col=lane&15, row=(lane>>4)*4+j
    const int r0base = tileM + wr*128 + lk*4;
    const int cbase  = tileN + wc*64 + lrow;
    #pragma unroll
    for (int m = 0; m < 8; ++m){
        const int r0 = r0base + m*16;
        #pragma unroll
        for (int n = 0; n < 4; ++n){
            const int c = cbase + n*16;
            f32x4 v = acc[m][n];
            #pragma unroll
            for (int j = 0; j < 4; ++j){
                float val = v[j] * scale;
                if (BIAS_MODE == 1) val += bias[c];
                if (BIAS_MODE == 2) val += bias[r0 + j];
                if (OUT_F32) Cf[(long)(r0 + j) * N + c] = val;
                else         Cm[(long)(r0 + j) * N + c] = f2bf(val);
            }
        }
    }
}

// ---------------- row softmax, in-place on bf16 [rows x 2048] ----------------
__global__ __launch_bounds__(256) void k_softmax(u16* __restrict__ P){
    u16* p = P + (long)blockIdx.x * Cc;
    const int tid = threadIdx.x;
    short8 raw = *(const short8*)(p + tid * 8);
    float v[8];
    float mx = -3.0e38f;
    #pragma unroll
    for (int i = 0; i < 8; ++i){ v[i] = bf2f((u16)raw[i]); mx = fmaxf(mx, v[i]); }
    #pragma unroll
    for (int o = 32; o > 0; o >>= 1) mx = fmaxf(mx, __shfl_xor(mx, o));
    __shared__ float redm[4];
    if ((tid & 63) == 0) redm[tid >> 6] = mx;
    __syncthreads();
    mx = fmaxf(fmaxf(redm[0], redm[1]), fmaxf(redm[2], redm[3]));
    float s = 0.f;
    #pragma unroll
    for (int i = 0; i < 8; ++i){ v[i] = __expf(v[i] - mx); s += v[i]; }
    #pragma unroll
    for (int o = 32; o > 0; o >>= 1) s += __shfl_xor(s, o);
    __shared__ float reds[4];
    if ((tid & 63) == 0) reds[tid >> 6] = s;
    __syncthreads();
    s = reds[0] + reds[1] + reds[2] + reds[3];
    const float inv = 1.f / s;
    short8 o8;
    #pragma unroll
    for (int i = 0; i < 8; ++i) o8[i] = (short)f2bf(v[i] * inv);
    *(short8*)(p + tid * 8) = o8;
}

static inline int cast_grid(long n4){
    long g = (n4 + 255) / 256;
    return (int)(g > 2048 ? 2048 : g);
}

extern "C" void kernel_launch(void* const* d_in, const int* in_sizes, int n_in,
                              void* d_out, int out_size, void* d_ws, size_t ws_size,
                              hipStream_t stream)
{
    const float* x     = (const float*)d_in[0];
    const float* fc_w  = (const float*)d_in[1];
    const float* fc_b  = (const float*)d_in[2];
    const float* altw  = (const float*)d_in[3];
    const float* altb  = (const float*)d_in[4];
    const float* vfc_w = (const float*)d_in[5];
    const float* vfc_b = (const float*)d_in[6];
    float* out = (float*)d_out;   // reference output is fp32

    char* ws = (char*)d_ws;
    const size_t nBCE = (size_t)Bb * Cc * Ee;            // 16,777,216 elements
    u16* xb   = (u16*)(ws);                              // [B][C][E]
    u16* xbT  = (u16*)(ws + 2 * nBCE);                   // [B][E][C]
    u16* P    = (u16*)(ws);                              // [B][C][C] (aliases xb+xbT, dead by then)
    u16* y    = (u16*)(ws + 4 * nBCE);                   // [B][C][E]
    u16* z    = (u16*)(ws + 6 * nBCE);                   // [B][C][E]   z[b][k][e] = yx[b,e,k]
    u16* vxT  = (u16*)(ws + 8 * nBCE);                   // [B][E][C]   vxT[b][f][k] = vx[b,k,f]
    u16* fcwb = (u16*)(ws + 10 * nBCE);                  // [E][E]
    u16* vfwb = fcwb + (size_t)Ee * Ee;
    u16* awb  = vfwb + (size_t)Ee * Ee;                  // [C][C]

    // 1) casts (x: fused straight+transpose, single fp32 read)
    k_cast_xt<<<dim3(Ee / 32, Cc / 32, Bb), 256, 0, stream>>>(x, xb, xbT);
    k_cast<<<cast_grid((long)Ee * Ee / 4), 256, 0, stream>>>(fc_w, fcwb, (long)Ee * Ee / 4);
    k_cast<<<cast_grid((long)Ee * Ee / 4), 256, 0, stream>>>(vfc_w, vfwb, (long)Ee * Ee / 4);
    k_cast<<<cast_grid((long)Cc * Cc / 4), 256, 0, stream>>>(altw, awb, (long)Cc * Cc / 4);

    const long sBCE = (long)Cc * Ee;
    const long sBCC = (long)Cc * Cc;
    dim3 blk(512);

    // 2) y[b][c][f] = sum_e xb[c,e] fcw[f,e] + fc_b[f]        M=C,N=E,K=E
    k_gemm256<1, 0><<<dim3(Cc/256, Ee/256, Bb), blk, 0, stream>>>(
        xb, fcwb, y, fc_b, Ee, Ee, sBCE, 0, sBCE, 1.f);

    // 3) vxT[b][f][k] = sum_e vfcw[f,e] xb[k,e] + vfc_b[f]    M=E,N=C,K=E (bias per row)
    k_gemm256<2, 0><<<dim3(Ee/256, Cc/256, Bb), blk, 0, stream>>>(
        vfwb, xb, vxT, vfc_b, Cc, Ee, 0, sBCE, sBCE, 1.f);

    // 4) z[b][k][e] = sum_c altw[k,c] xT[e,c] + alt_b[k]      M=C,N=E,K=C (bias per row)
    k_gemm256<2, 0><<<dim3(Cc/256, Ee/256, Bb), blk, 0, stream>>>(
        awb, xbT, z, altb, Ee, Cc, 0, sBCE, sBCE, 1.f);

    // 5) P[b][c][k] = (1/sqrt(C)) * sum_e y[c,e] z[k,e]       M=C,N=C,K=E
    k_gemm256<0, 0><<<dim3(Cc/256, Cc/256, Bb), blk, 0, stream>>>(
        y, z, P, nullptr, Cc, Ee, sBCE, sBCE, sBCC, 0.022097086912079608f);

    // 6) softmax rows of P (in place)
    k_softmax<<<Bb * Cc, 256, 0, stream>>>(P);

    // 7) out[b][c][e] = sum_k P[c,k] vxT[e,k] -> fp32         M=C,N=E,K=C
    k_gemm256<0, 1><<<dim3(Cc/256, Ee/256, Bb), blk, 0, stream>>>(
        P, vxT, out, nullptr, Ee, Cc, sBCC, sBCE, sBCE, 1.f);
}

// Round 5
// 348.889 us; speedup vs baseline: 1.5115x; 1.0132x over previous
//
#include <hip/hip_runtime.h>
#include <stdint.h>

#define Bb 8
#define Cc 2048
#define Ee 1024

typedef unsigned short u16;
typedef __attribute__((ext_vector_type(8))) short short8;
typedef __attribute__((ext_vector_type(4))) float f32x4;

__device__ __forceinline__ u16 f2bf(float f){
    unsigned u = __builtin_bit_cast(unsigned, f);
    return (u16)((u + 0x7fffu + ((u >> 16) & 1u)) >> 16);   // RNE, finite inputs
}
__device__ __forceinline__ float bf2f(u16 h){
    return __builtin_bit_cast(float, ((unsigned)h) << 16);
}
__device__ __forceinline__ void gld16(const void* g, void* l){
    __builtin_amdgcn_global_load_lds(
        (const __attribute__((address_space(1))) unsigned int*)g,
        (__attribute__((address_space(3))) unsigned int*)l,
        16, 0, 0);
}
#define MFMA(a,b,c) __builtin_amdgcn_mfma_f32_16x16x32_bf16((a),(b),(c),0,0,0)
#define SBAR()  __builtin_amdgcn_s_barrier()
#define SCHED0() __builtin_amdgcn_sched_barrier(0)
#define LGKM0() asm volatile("s_waitcnt lgkmcnt(0)" ::: "memory")
#define VMCNT6() asm volatile("s_waitcnt vmcnt(6)" ::: "memory")
#define VMCNT2() asm volatile("s_waitcnt vmcnt(2)" ::: "memory")
#define VMCNT0() asm volatile("s_waitcnt vmcnt(0)" ::: "memory")

// ---------------- cast fp32 -> bf16 (vectorized) ----------------
__global__ __launch_bounds__(256) void k_cast(const float* __restrict__ s,
                                              u16* __restrict__ d, long n4){
    long i = (long)blockIdx.x * 256 + threadIdx.x;
    const long stride = (long)gridDim.x * 256;
    for (; i < n4; i += stride){
        float4 f = ((const float4*)s)[i];
        ushort4 o = make_ushort4(f2bf(f.x), f2bf(f.y), f2bf(f.z), f2bf(f.w));
        ((ushort4*)d)[i] = o;
    }
}

// ------ fused: x fp32 -> xb bf16 (straight) + xbT bf16 (transposed) ------
__global__ __launch_bounds__(256) void k_cast_xt(const float* __restrict__ src,
                                                 u16* __restrict__ xb,
                                                 u16* __restrict__ xbT){
    __shared__ float tile[32][33];
    const int b = blockIdx.z;
    src += (long)b * Cc * Ee;
    xb  += (long)b * Cc * Ee;
    xbT += (long)b * Cc * Ee;
    const int c0 = blockIdx.x * 32;   // E-dim block
    const int r0 = blockIdx.y * 32;   // C-dim block
    const int tx = threadIdx.x & 31;
    const int ty = threadIdx.x >> 5;  // 0..7
    #pragma unroll
    for (int p = 0; p < 4; ++p){
        float v = src[(long)(r0 + ty + p*8) * Ee + c0 + tx];
        tile[ty + p*8][tx] = v;
        xb[(long)(r0 + ty + p*8) * Ee + c0 + tx] = f2bf(v);
    }
    __syncthreads();
    #pragma unroll
    for (int p = 0; p < 4; ++p)
        xbT[(long)(c0 + ty + p*8) * Cc + r0 + tx] = f2bf(tile[tx][ty + p*8]);
}

// =============== 256x256 8-phase NT GEMM (kk-major, slack-scheduled vmcnt) ===============
// C[m,n] = scale * sum_k A[m,k]*B[n,k] (+bias); A:[M,K], B:[N,K] bf16 row-major.
// 512 thr = 8 waves (2M x 4N); BK=64; LDS 128KiB double-buffered.
// Phases: p1 (m0-3,kk0: 8 rd), p2 (m0-3,kk1: 8 rd), p3 (m4-7,kk0: 4 rd, B reuse),
//         p4 (m4-7,kk1: 4 rd, B reuse).
// Staging for tile t+1: p1: A0,A2,B0,B1 (4 loads) | p2: B2,B3 | p3: none | p4: A1,A3.
// Waits: p2-end vmcnt(6) covers A1,A3(t)   [issued p4(t-1), 2-phase slack];
//        p4-end vmcnt(2) covers A0,A2,B0-3(t+1) [issued p1/p2(t), >=2-phase slack].
// Never drains to 0 in steady state; last tile uses vmcnt(0) at p2-end.
// LDS swizzle: 16B-chunk c at c ^ (row&7); pre-swizzled global source.
// BIAS_MODE: 0 none, 1 bias[col], 2 bias[row].  OUT_F32: fp32 out else bf16.
template<int BIAS_MODE, int OUT_F32>
__global__ __launch_bounds__(512, 2)
void k_gemm256(const u16* __restrict__ A, const u16* __restrict__ Bm,
               void* __restrict__ Cout, const float* __restrict__ bias,
               int N, int K, long sA, long sB, long sC, float scale)
{
    __shared__ __attribute__((aligned(16))) char smem[131072];

    // ---- bijective XCD swizzle (nwg % 8 == 0 for all launches here)
    const int gx = gridDim.x, gy = gridDim.y;
    const int nwg = gx * gy * gridDim.z;
    const int lin = blockIdx.x + gx * (blockIdx.y + gy * blockIdx.z);
    const int swz = (lin & 7) * (nwg >> 3) + (lin >> 3);
    const int bx = swz % gx;
    const int tmp = swz / gx;
    const int by = tmp % gy;
    const int bz = tmp / gy;

    A  += (long)bz * sA;
    Bm += (long)bz * sB;
    u16*   Cm = (u16*)Cout + (OUT_F32 ? 0 : (long)bz * sC);
    float* Cf = (float*)Cout + (OUT_F32 ? (long)bz * sC : 0);

    const int tid  = threadIdx.x;
    const int lane = tid & 63;
    const int wave = tid >> 6;
    const int wr = wave >> 2;          // 0..1  (M half)
    const int wc = wave & 3;           // 0..3  (N quarter)
    const int tileM = bx * 256;
    const int tileN = by * 256;

    // ---- staging constants: unit = 64 rows x 64 cols (8KiB) = 1 gld16/thread
    const int srow   = tid >> 3;                 // 0..63 (row within unit)
    const int schunk = (tid & 7) ^ (srow & 7);   // pre-swizzled 16B chunk
    const u16* Ag = A  + (long)(tileM + srow) * K + schunk * 8;
    const u16* Bg = Bm + (long)(tileN + srow) * K + schunk * 8;
    const long uK = (long)64 * K;                // global stride per unit
    const int  ldst = tid * 16;                  // linear LDS dest

    // ---- ds_read constants (swizzled chunk)
    const int lrow = lane & 15;
    const int lk   = lane >> 4;                  // 0..3
    const int sw   = lrow & 7;
    const int cs0  = ((0 + lk) ^ sw) * 16;       // kk=0 chunk byte
    const int cs1  = ((4 + lk) ^ sw) * 16;       // kk=1 chunk byte
    const int arow0 = (wr*128 + lrow) * 128;             // A row byte off in tile
    const int brow0 = 32768 + (wc*64 + lrow) * 128;      // B row byte off in tile

    f32x4 acc[8][4];
    #pragma unroll
    for (int m = 0; m < 8; ++m)
        #pragma unroll
        for (int n = 0; n < 4; ++n)
            acc[m][n] = (f32x4){0.f,0.f,0.f,0.f};

    char* sm = smem;
    // ---- prologue: stage tile 0 into buf0, full drain (one-time)
    #pragma unroll
    for (int u = 0; u < 4; ++u) gld16(Bg + u*uK, sm + 32768 + u*8192 + ldst);
    #pragma unroll
    for (int u = 0; u < 4; ++u) gld16(Ag + u*uK, sm + u*8192 + ldst);
    __syncthreads();

    const int NT = K >> 6;
    short8 aF[4], bK0[4], bK1[4];

    for (int t = 0; t < NT; ++t){
        const bool pref = (t + 1) < NT;
        char* cbuf = sm + ((t & 1) << 16);
        char* nbuf = sm + (((t + 1) & 1) << 16);
        const u16* Agt = Ag + (long)(t + 1) * 64;
        const u16* Bgt = Bg + (long)(t + 1) * 64;

        // ===== p1: (m0-3, kk0) — 8 reads; stage A0,A2,B0,B1 =====
        #pragma unroll
        for (int m = 0; m < 4; ++m) aF[m]  = *(const short8*)(cbuf + arow0 + m*2048 + cs0);
        #pragma unroll
        for (int n = 0; n < 4; ++n) bK0[n] = *(const short8*)(cbuf + brow0 + n*2048 + cs0);
        if (pref){ gld16(Agt + 0*uK, nbuf + 0*8192 + ldst);
                   gld16(Agt + 2*uK, nbuf + 2*8192 + ldst);
                   gld16(Bgt + 0*uK, nbuf + 32768 + 0*8192 + ldst);
                   gld16(Bgt + 1*uK, nbuf + 32768 + 1*8192 + ldst); }
        SCHED0(); SBAR(); LGKM0(); SCHED0();
        __builtin_amdgcn_s_setprio(1);
        #pragma unroll
        for (int m = 0; m < 4; ++m)
            #pragma unroll
            for (int n = 0; n < 4; ++n)
                acc[m][n] = MFMA(aF[m], bK0[n], acc[m][n]);
        __builtin_amdgcn_s_setprio(0);
        SBAR(); SCHED0();

        // ===== p2: (m0-3, kk1) — 8 reads; stage B2,B3; W2 wait =====
        #pragma unroll
        for (int m = 0; m < 4; ++m) aF[m]  = *(const short8*)(cbuf + arow0 + m*2048 + cs1);
        #pragma unroll
        for (int n = 0; n < 4; ++n) bK1[n] = *(const short8*)(cbuf + brow0 + n*2048 + cs1);
        if (pref){ gld16(Bgt + 2*uK, nbuf + 32768 + 2*8192 + ldst);
                   gld16(Bgt + 3*uK, nbuf + 32768 + 3*8192 + ldst); }
        SCHED0(); SBAR(); LGKM0(); SCHED0();
        __builtin_amdgcn_s_setprio(1);
        #pragma unroll
        for (int m = 0; m < 4; ++m)
            #pragma unroll
            for (int n = 0; n < 4; ++n)
                acc[m][n] = MFMA(aF[m], bK1[n], acc[m][n]);
        __builtin_amdgcn_s_setprio(0);
        if (pref){ VMCNT6(); } else { VMCNT0(); }   // A1,A3 of cur tile landed (2-phase slack)
        SBAR(); SCHED0();

        // ===== p3: (m4-7, kk0) — 4 reads (bK0 reuse); no stage =====
        #pragma unroll
        for (int m = 0; m < 4; ++m) aF[m] = *(const short8*)(cbuf + arow0 + (m+4)*2048 + cs0);
        SCHED0(); SBAR(); LGKM0(); SCHED0();
        __builtin_amdgcn_s_setprio(1);
        #pragma unroll
        for (int m = 0; m < 4; ++m)
            #pragma unroll
            for (int n = 0; n < 4; ++n)
                acc[m+4][n] = MFMA(aF[m], bK0[n], acc[m+4][n]);
        __builtin_amdgcn_s_setprio(0);
        SBAR(); SCHED0();

        // ===== p4: (m4-7, kk1) — 4 reads (bK1 reuse); stage A1,A3; W1 wait =====
        #pragma unroll
        for (int m = 0; m < 4; ++m) aF[m] = *(const short8*)(cbuf + arow0 + (m+4)*2048 + cs1);
        if (pref){ gld16(Agt + 1*uK, nbuf + 1*8192 + ldst);
                   gld16(Agt + 3*uK, nbuf + 3*8192 + ldst); }
        SCHED0(); SBAR(); LGKM0(); SCHED0();
        __builtin_amdgcn_s_setprio(1);
        #pragma unroll
        for (int m = 0; m < 4; ++m)
            #pragma unroll
            for (int n = 0; n < 4; ++n)
                acc[m+4][n] = MFMA(aF[m], bK1[n], acc[m+4][n]);
        __builtin_amdgcn_s_setprio(0);
        if (pref){ VMCNT2(); }                      // next tile's A0,A2,B0-3 landed (>=2-phase slack)
        SBAR(); SCHED0();
    }

    // ---- epilogue: C/D layout col=lane&15, row=(lane>>4)*4+j
    const int r0base = tileM + wr*128 + lk*4;
    const int cbase  = tileN + wc*64 + lrow;
    #pragma unroll
    for (int m = 0; m < 8; ++m){
        const int r0 = r0base + m*16;
        #pragma unroll
        for (int n = 0; n < 4; ++n){
            const int c = cbase + n*16;
            f32x4 v = acc[m][n];
            #pragma unroll
            for (int j = 0; j < 4; ++j){
                float val = v[j] * scale;
                if (BIAS_MODE == 1) val += bias[c];
                if (BIAS_MODE == 2) val += bias[r0 + j];
                if (OUT_F32) Cf[(long)(r0 + j) * N + c] = val;
                else         Cm[(long)(r0 + j) * N + c] = f2bf(val);
            }
        }
    }
}

// ---------------- row softmax, in-place on bf16 [rows x 2048] ----------------
__global__ __launch_bounds__(256) void k_softmax(u16* __restrict__ P){
    u16* p = P + (long)blockIdx.x * Cc;
    const int tid = threadIdx.x;
    short8 raw = *(const short8*)(p + tid * 8);
    float v[8];
    float mx = -3.0e38f;
    #pragma unroll
    for (int i = 0; i < 8; ++i){ v[i] = bf2f((u16)raw[i]); mx = fmaxf(mx, v[i]); }
    #pragma unroll
    for (int o = 32; o > 0; o >>= 1) mx = fmaxf(mx, __shfl_xor(mx, o));
    __shared__ float redm[4];
    if ((tid & 63) == 0) redm[tid >> 6] = mx;
    __syncthreads();
    mx = fmaxf(fmaxf(redm[0], redm[1]), fmaxf(redm[2], redm[3]));
    float s = 0.f;
    #pragma unroll
    for (int i = 0; i < 8; ++i){ v[i] = __expf(v[i] - mx); s += v[i]; }
    #pragma unroll
    for (int o = 32; o > 0; o >>= 1) s += __shfl_xor(s, o);
    __shared__ float reds[4];
    if ((tid & 63) == 0) reds[tid >> 6] = s;
    __syncthreads();
    s = reds[0] + reds[1] + reds[2] + reds[3];
    const float inv = 1.f / s;
    short8 o8;
    #pragma unroll
    for (int i = 0; i < 8; ++i) o8[i] = (short)f2bf(v[i] * inv);
    *(short8*)(p + tid * 8) = o8;
}

static inline int cast_grid(long n4){
    long g = (n4 + 255) / 256;
    return (int)(g > 2048 ? 2048 : g);
}

extern "C" void kernel_launch(void* const* d_in, const int* in_sizes, int n_in,
                              void* d_out, int out_size, void* d_ws, size_t ws_size,
                              hipStream_t stream)
{
    const float* x     = (const float*)d_in[0];
    const float* fc_w  = (const float*)d_in[1];
    const float* fc_b  = (const float*)d_in[2];
    const float* altw  = (const float*)d_in[3];
    const float* altb  = (const float*)d_in[4];
    const float* vfc_w = (const float*)d_in[5];
    const float* vfc_b = (const float*)d_in[6];
    float* out = (float*)d_out;   // reference output is fp32

    char* ws = (char*)d_ws;
    const size_t nBCE = (size_t)Bb * Cc * Ee;            // 16,777,216 elements
    u16* xb   = (u16*)(ws);                              // [B][C][E]
    u16* xbT  = (u16*)(ws + 2 * nBCE);                   // [B][E][C]
    u16* P    = (u16*)(ws);                              // [B][C][C] (aliases xb+xbT, dead by then)
    u16* y    = (u16*)(ws + 4 * nBCE);                   // [B][C][E]
    u16* z    = (u16*)(ws + 6 * nBCE);                   // [B][C][E]   z[b][k][e] = yx[b,e,k]
    u16* vxT  = (u16*)(ws + 8 * nBCE);                   // [B][E][C]   vxT[b][f][k] = vx[b,k,f]
    u16* fcwb = (u16*)(ws + 10 * nBCE);                  // [E][E]
    u16* vfwb = fcwb + (size_t)Ee * Ee;
    u16* awb  = vfwb + (size_t)Ee * Ee;                  // [C][C]

    // 1) casts (x: fused straight+transpose, single fp32 read)
    k_cast_xt<<<dim3(Ee / 32, Cc / 32, Bb), 256, 0, stream>>>(x, xb, xbT);
    k_cast<<<cast_grid((long)Ee * Ee / 4), 256, 0, stream>>>(fc_w, fcwb, (long)Ee * Ee / 4);
    k_cast<<<cast_grid((long)Ee * Ee / 4), 256, 0, stream>>>(vfc_w, vfwb, (long)Ee * Ee / 4);
    k_cast<<<cast_grid((long)Cc * Cc / 4), 256, 0, stream>>>(altw, awb, (long)Cc * Cc / 4);

    const long sBCE = (long)Cc * Ee;
    const long sBCC = (long)Cc * Cc;
    dim3 blk(512);

    // 2) y[b][c][f] = sum_e xb[c,e] fcw[f,e] + fc_b[f]        M=C,N=E,K=E
    k_gemm256<1, 0><<<dim3(Cc/256, Ee/256, Bb), blk, 0, stream>>>(
        xb, fcwb, y, fc_b, Ee, Ee, sBCE, 0, sBCE, 1.f);

    // 3) vxT[b][f][k] = sum_e vfcw[f,e] xb[k,e] + vfc_b[f]    M=E,N=C,K=E (bias per row)
    k_gemm256<2, 0><<<dim3(Ee/256, Cc/256, Bb), blk, 0, stream>>>(
        vfwb, xb, vxT, vfc_b, Cc, Ee, 0, sBCE, sBCE, 1.f);

    // 4) z[b][k][e] = sum_c altw[k,c] xT[e,c] + alt_b[k]      M=C,N=E,K=C (bias per row)
    k_gemm256<2, 0><<<dim3(Cc/256, Ee/256, Bb), blk, 0, stream>>>(
        awb, xbT, z, altb, Ee, Cc, 0, sBCE, sBCE, 1.f);

    // 5) P[b][c][k] = (1/sqrt(C)) * sum_e y[c,e] z[k,e]       M=C,N=C,K=E
    k_gemm256<0, 0><<<dim3(Cc/256, Cc/256, Bb), blk, 0, stream>>>(
        y, z, P, nullptr, Cc, Ee, sBCE, sBCE, sBCC, 0.022097086912079608f);

    // 6) softmax rows of P (in place)
    k_softmax<<<Bb * Cc, 256, 0, stream>>>(P);

    // 7) out[b][c][e] = sum_k P[c,k] vxT[e,k] -> fp32         M=C,N=E,K=C
    k_gemm256<0, 1><<<dim3(Cc/256, Ee/256, Bb), blk, 0, stream>>>(
        P, vxT, out, nullptr, Ee, Cc, sBCC, sBCE, sBCE, 1.f);
}

// Round 6
// 340.643 us; speedup vs baseline: 1.5481x; 1.0242x over previous
//
#include <hip/hip_runtime.h>
#include <stdint.h>

#define Bb 8
#define Cc 2048
#define Ee 1024

typedef unsigned short u16;
typedef __attribute__((ext_vector_type(8))) short short8;
typedef __attribute__((ext_vector_type(4))) float f32x4;

__device__ __forceinline__ u16 f2bf(float f){
    unsigned u = __builtin_bit_cast(unsigned, f);
    return (u16)((u + 0x7fffu + ((u >> 16) & 1u)) >> 16);   // RNE, finite inputs
}
__device__ __forceinline__ float bf2f(u16 h){
    return __builtin_bit_cast(float, ((unsigned)h) << 16);
}
__device__ __forceinline__ void gld16(const void* g, void* l){
    __builtin_amdgcn_global_load_lds(
        (const __attribute__((address_space(1))) unsigned int*)g,
        (__attribute__((address_space(3))) unsigned int*)l,
        16, 0, 0);
}
#define MFMA(a,b,c) __builtin_amdgcn_mfma_f32_16x16x32_bf16((a),(b),(c),0,0,0)
#define SBAR()  __builtin_amdgcn_s_barrier()
#define SCHED0() __builtin_amdgcn_sched_barrier(0)
#define LGKM8() asm volatile("s_waitcnt lgkmcnt(8)" ::: "memory")
#define LGKM4() asm volatile("s_waitcnt lgkmcnt(4)" ::: "memory")
#define LGKM0() asm volatile("s_waitcnt lgkmcnt(0)" ::: "memory")
#define VMCNT0() asm volatile("s_waitcnt vmcnt(0)" ::: "memory")

// ---------------- cast fp32 -> bf16 (vectorized) ----------------
__global__ __launch_bounds__(256) void k_cast(const float* __restrict__ s,
                                              u16* __restrict__ d, long n4){
    long i = (long)blockIdx.x * 256 + threadIdx.x;
    const long stride = (long)gridDim.x * 256;
    for (; i < n4; i += stride){
        float4 f = ((const float4*)s)[i];
        ushort4 o = make_ushort4(f2bf(f.x), f2bf(f.y), f2bf(f.z), f2bf(f.w));
        ((ushort4*)d)[i] = o;
    }
}

// ------ fused: x fp32 -> xb bf16 (straight) + xbT bf16 (transposed) ------
__global__ __launch_bounds__(256) void k_cast_xt(const float* __restrict__ src,
                                                 u16* __restrict__ xb,
                                                 u16* __restrict__ xbT){
    __shared__ float tile[32][33];
    const int b = blockIdx.z;
    src += (long)b * Cc * Ee;
    xb  += (long)b * Cc * Ee;
    xbT += (long)b * Cc * Ee;
    const int c0 = blockIdx.x * 32;   // E-dim block
    const int r0 = blockIdx.y * 32;   // C-dim block
    const int tx = threadIdx.x & 31;
    const int ty = threadIdx.x >> 5;  // 0..7
    #pragma unroll
    for (int p = 0; p < 4; ++p){
        float v = src[(long)(r0 + ty + p*8) * Ee + c0 + tx];
        tile[ty + p*8][tx] = v;
        xb[(long)(r0 + ty + p*8) * Ee + c0 + tx] = f2bf(v);
    }
    __syncthreads();
    #pragma unroll
    for (int p = 0; p < 4; ++p)
        xbT[(long)(c0 + ty + p*8) * Cc + r0 + tx] = f2bf(tile[tx][ty + p*8]);
}

// =============== 256x256 NT GEMM — 1 barrier/K-tile, per-wave SW pipeline ===============
// C[m,n] = scale * sum_k A[m,k]*B[n,k] (+bias); A:[M,K], B:[N,K] bf16 row-major.
// 512 thr = 8 waves (2M x 4N); BK=64; LDS 128KiB double-buffered.
// Per K-tile (per wave): issue 8 gld16 for t+1 at tile start (lands well before
// tile-end vmcnt(0) since tile compute ~3k cyc >> L2 latency);
// quadrant pipeline q0(m0-3,kk0) q1(m0-3,kk1) q2(m4-7,kk0) q3(m4-7,kk1):
// reads for q+1 issue before MFMA(q), gated by counted lgkmcnt (FIFO DS returns):
//   [q0+q1 reads:16] lgkm(8) MFMA(q0) [q2 reads:4] lgkm(4) MFMA(q1)
//   [q3 reads:4] lgkm(4) MFMA(q2) lgkm(0) MFMA(q3)  -> vmcnt(0) barrier.
// sched_barrier(0) after each wait (rule: MFMA hoists past asm lgkm otherwise).
// No per-phase barriers: LDS reads overlap MFMA across/within waves.
// LDS swizzle: 16B-chunk c at c ^ (row&7); pre-swizzled global source (0 conflicts).
// BIAS_MODE: 0 none, 1 bias[col], 2 bias[row].  OUT_F32: fp32 out else bf16.
template<int BIAS_MODE, int OUT_F32>
__global__ __launch_bounds__(512, 2)
void k_gemm256(const u16* __restrict__ A, const u16* __restrict__ Bm,
               void* __restrict__ Cout, const float* __restrict__ bias,
               int N, int K, long sA, long sB, long sC, float scale)
{
    __shared__ __attribute__((aligned(16))) char smem[131072];

    // ---- bijective XCD swizzle (nwg % 8 == 0 for all launches here)
    const int gx = gridDim.x, gy = gridDim.y;
    const int nwg = gx * gy * gridDim.z;
    const int lin = blockIdx.x + gx * (blockIdx.y + gy * blockIdx.z);
    const int swz = (lin & 7) * (nwg >> 3) + (lin >> 3);
    const int bx = swz % gx;
    const int tmp = swz / gx;
    const int by = tmp % gy;
    const int bz = tmp / gy;

    A  += (long)bz * sA;
    Bm += (long)bz * sB;
    u16*   Cm = (u16*)Cout + (OUT_F32 ? 0 : (long)bz * sC);
    float* Cf = (float*)Cout + (OUT_F32 ? (long)bz * sC : 0);

    const int tid  = threadIdx.x;
    const int lane = tid & 63;
    const int wave = tid >> 6;
    const int wr = wave >> 2;          // 0..1  (M half)
    const int wc = wave & 3;           // 0..3  (N quarter)
    const int tileM = bx * 256;
    const int tileN = by * 256;

    // ---- staging constants: unit = 64 rows x 64 cols (8KiB) = 1 gld16/thread
    const int srow   = tid >> 3;                 // 0..63 (row within unit)
    const int schunk = (tid & 7) ^ (srow & 7);   // pre-swizzled 16B chunk
    const u16* Ag = A  + (long)(tileM + srow) * K + schunk * 8;
    const u16* Bg = Bm + (long)(tileN + srow) * K + schunk * 8;
    const long uK = (long)64 * K;                // global stride per unit
    const int  ldst = tid * 16;                  // linear LDS dest

    // ---- ds_read constants (swizzled chunk)
    const int lrow = lane & 15;
    const int lk   = lane >> 4;                  // 0..3
    const int sw   = lrow & 7;
    const int cs0  = ((0 + lk) ^ sw) * 16;       // kk=0 chunk byte
    const int cs1  = ((4 + lk) ^ sw) * 16;       // kk=1 chunk byte
    const int arow0 = (wr*128 + lrow) * 128;             // A row byte off in tile
    const int brow0 = 32768 + (wc*64 + lrow) * 128;      // B row byte off in tile

    f32x4 acc[8][4];
    #pragma unroll
    for (int m = 0; m < 8; ++m)
        #pragma unroll
        for (int n = 0; n < 4; ++n)
            acc[m][n] = (f32x4){0.f,0.f,0.f,0.f};

    char* sm = smem;
    // ---- prologue: stage tile 0 into buf0, full drain (one-time)
    #pragma unroll
    for (int u = 0; u < 4; ++u) gld16(Bg + u*uK, sm + 32768 + u*8192 + ldst);
    #pragma unroll
    for (int u = 0; u < 4; ++u) gld16(Ag + u*uK, sm + u*8192 + ldst);
    __syncthreads();

    const int NT = K >> 6;
    short8 aA[4], aB[4], bK0[4], bK1[4];

    for (int t = 0; t < NT; ++t){
        const bool pref = (t + 1) < NT;
        char* cbuf = sm + ((t & 1) << 16);
        char* nbuf = sm + (((t + 1) & 1) << 16);
        const u16* Agt = Ag + (long)(t + 1) * 64;
        const u16* Bgt = Bg + (long)(t + 1) * 64;

        // ---- issue next tile's staging up-front (8 loads; land during compute)
        if (pref){
            gld16(Agt + 0*uK, nbuf + 0*8192 + ldst);
            gld16(Agt + 1*uK, nbuf + 1*8192 + ldst);
            gld16(Agt + 2*uK, nbuf + 2*8192 + ldst);
            gld16(Agt + 3*uK, nbuf + 3*8192 + ldst);
            gld16(Bgt + 0*uK, nbuf + 32768 + 0*8192 + ldst);
            gld16(Bgt + 1*uK, nbuf + 32768 + 1*8192 + ldst);
            gld16(Bgt + 2*uK, nbuf + 32768 + 2*8192 + ldst);
            gld16(Bgt + 3*uK, nbuf + 32768 + 3*8192 + ldst);
        }

        // ---- q0 + q1 reads (16 ds_read_b128)
        #pragma unroll
        for (int m = 0; m < 4; ++m) aA[m]  = *(const short8*)(cbuf + arow0 + m*2048 + cs0);
        #pragma unroll
        for (int n = 0; n < 4; ++n) bK0[n] = *(const short8*)(cbuf + brow0 + n*2048 + cs0);
        #pragma unroll
        for (int m = 0; m < 4; ++m) aB[m]  = *(const short8*)(cbuf + arow0 + m*2048 + cs1);
        #pragma unroll
        for (int n = 0; n < 4; ++n) bK1[n] = *(const short8*)(cbuf + brow0 + n*2048 + cs1);

        LGKM8(); SCHED0();                       // q0 frags ready
        __builtin_amdgcn_s_setprio(1);
        #pragma unroll
        for (int m = 0; m < 4; ++m)
            #pragma unroll
            for (int n = 0; n < 4; ++n)
                acc[m][n] = MFMA(aA[m], bK0[n], acc[m][n]);
        __builtin_amdgcn_s_setprio(0);

        // ---- q2 reads (4) — interleaves with q0 MFMAs above per scheduler
        #pragma unroll
        for (int m = 0; m < 4; ++m) aA[m] = *(const short8*)(cbuf + arow0 + (m+4)*2048 + cs0);
        LGKM4(); SCHED0();                       // q1 frags ready (only q2's 4 remain)
        __builtin_amdgcn_s_setprio(1);
        #pragma unroll
        for (int m = 0; m < 4; ++m)
            #pragma unroll
            for (int n = 0; n < 4; ++n)
                acc[m][n] = MFMA(aB[m], bK1[n], acc[m][n]);
        __builtin_amdgcn_s_setprio(0);

        // ---- q3 reads (4)
        #pragma unroll
        for (int m = 0; m < 4; ++m) aB[m] = *(const short8*)(cbuf + arow0 + (m+4)*2048 + cs1);
        LGKM4(); SCHED0();                       // q2 frags ready (only q3's 4 remain)
        __builtin_amdgcn_s_setprio(1);
        #pragma unroll
        for (int m = 0; m < 4; ++m)
            #pragma unroll
            for (int n = 0; n < 4; ++n)
                acc[m+4][n] = MFMA(aA[m], bK0[n], acc[m+4][n]);
        __builtin_amdgcn_s_setprio(0);

        LGKM0(); SCHED0();                       // q3 frags ready
        __builtin_amdgcn_s_setprio(1);
        #pragma unroll
        for (int m = 0; m < 4; ++m)
            #pragma unroll
            for (int n = 0; n < 4; ++n)
                acc[m+4][n] = MFMA(aB[m], bK1[n], acc[m+4][n]);
        __builtin_amdgcn_s_setprio(0);

        // ---- tile boundary: own staging landed (issued ~1 tile ago) + all waves done
        VMCNT0(); SBAR(); SCHED0();
    }

    // ---- epilogue: C/D layout col=lane&15, row=(lane>>4)*4+j
    const int r0base = tileM + wr*128 + lk*4;
    const int cbase  = tileN + wc*64 + lrow;
    #pragma unroll
    for (int m = 0; m < 8; ++m){
        const int r0 = r0base + m*16;
        #pragma unroll
        for (int n = 0; n < 4; ++n){
            const int c = cbase + n*16;
            f32x4 v = acc[m][n];
            #pragma unroll
            for (int j = 0; j < 4; ++j){
                float val = v[j] * scale;
                if (BIAS_MODE == 1) val += bias[c];
                if (BIAS_MODE == 2) val += bias[r0 + j];
                if (OUT_F32) Cf[(long)(r0 + j) * N + c] = val;
                else         Cm[(long)(r0 + j) * N + c] = f2bf(val);
            }
        }
    }
}

// ---------------- row softmax, in-place on bf16 [rows x 2048] ----------------
__global__ __launch_bounds__(256) void k_softmax(u16* __restrict__ P){
    u16* p = P + (long)blockIdx.x * Cc;
    const int tid = threadIdx.x;
    short8 raw = *(const short8*)(p + tid * 8);
    float v[8];
    float mx = -3.0e38f;
    #pragma unroll
    for (int i = 0; i < 8; ++i){ v[i] = bf2f((u16)raw[i]); mx = fmaxf(mx, v[i]); }
    #pragma unroll
    for (int o = 32; o > 0; o >>= 1) mx = fmaxf(mx, __shfl_xor(mx, o));
    __shared__ float redm[4];
    if ((tid & 63) == 0) redm[tid >> 6] = mx;
    __syncthreads();
    mx = fmaxf(fmaxf(redm[0], redm[1]), fmaxf(redm[2], redm[3]));
    float s = 0.f;
    #pragma unroll
    for (int i = 0; i < 8; ++i){ v[i] = __expf(v[i] - mx); s += v[i]; }
    #pragma unroll
    for (int o = 32; o > 0; o >>= 1) s += __shfl_xor(s, o);
    __shared__ float reds[4];
    if ((tid & 63) == 0) reds[tid >> 6] = s;
    __syncthreads();
    s = reds[0] + reds[1] + reds[2] + reds[3];
    const float inv = 1.f / s;
    short8 o8;
    #pragma unroll
    for (int i = 0; i < 8; ++i) o8[i] = (short)f2bf(v[i] * inv);
    *(short8*)(p + tid * 8) = o8;
}

static inline int cast_grid(long n4){
    long g = (n4 + 255) / 256;
    return (int)(g > 2048 ? 2048 : g);
}

extern "C" void kernel_launch(void* const* d_in, const int* in_sizes, int n_in,
                              void* d_out, int out_size, void* d_ws, size_t ws_size,
                              hipStream_t stream)
{
    const float* x     = (const float*)d_in[0];
    const float* fc_w  = (const float*)d_in[1];
    const float* fc_b  = (const float*)d_in[2];
    const float* altw  = (const float*)d_in[3];
    const float* altb  = (const float*)d_in[4];
    const float* vfc_w = (const float*)d_in[5];
    const float* vfc_b = (const float*)d_in[6];
    float* out = (float*)d_out;   // reference output is fp32

    char* ws = (char*)d_ws;
    const size_t nBCE = (size_t)Bb * Cc * Ee;            // 16,777,216 elements
    u16* xb   = (u16*)(ws);                              // [B][C][E]
    u16* xbT  = (u16*)(ws + 2 * nBCE);                   // [B][E][C]
    u16* P    = (u16*)(ws);                              // [B][C][C] (aliases xb+xbT, dead by then)
    u16* y    = (u16*)(ws + 4 * nBCE);                   // [B][C][E]
    u16* z    = (u16*)(ws + 6 * nBCE);                   // [B][C][E]   z[b][k][e] = yx[b,e,k]
    u16* vxT  = (u16*)(ws + 8 * nBCE);                   // [B][E][C]   vxT[b][f][k] = vx[b,k,f]
    u16* fcwb = (u16*)(ws + 10 * nBCE);                  // [E][E]
    u16* vfwb = fcwb + (size_t)Ee * Ee;
    u16* awb  = vfwb + (size_t)Ee * Ee;                  // [C][C]

    // 1) casts (x: fused straight+transpose, single fp32 read)
    k_cast_xt<<<dim3(Ee / 32, Cc / 32, Bb), 256, 0, stream>>>(x, xb, xbT);
    k_cast<<<cast_grid((long)Ee * Ee / 4), 256, 0, stream>>>(fc_w, fcwb, (long)Ee * Ee / 4);
    k_cast<<<cast_grid((long)Ee * Ee / 4), 256, 0, stream>>>(vfc_w, vfwb, (long)Ee * Ee / 4);
    k_cast<<<cast_grid((long)Cc * Cc / 4), 256, 0, stream>>>(altw, awb, (long)Cc * Cc / 4);

    const long sBCE = (long)Cc * Ee;
    const long sBCC = (long)Cc * Cc;
    dim3 blk(512);

    // 2) y[b][c][f] = sum_e xb[c,e] fcw[f,e] + fc_b[f]        M=C,N=E,K=E
    k_gemm256<1, 0><<<dim3(Cc/256, Ee/256, Bb), blk, 0, stream>>>(
        xb, fcwb, y, fc_b, Ee, Ee, sBCE, 0, sBCE, 1.f);

    // 3) vxT[b][f][k] = sum_e vfcw[f,e] xb[k,e] + vfc_b[f]    M=E,N=C,K=E (bias per row)
    k_gemm256<2, 0><<<dim3(Ee/256, Cc/256, Bb), blk, 0, stream>>>(
        vfwb, xb, vxT, vfc_b, Cc, Ee, 0, sBCE, sBCE, 1.f);

    // 4) z[b][k][e] = sum_c altw[k,c] xT[e,c] + alt_b[k]      M=C,N=E,K=C (bias per row)
    k_gemm256<2, 0><<<dim3(Cc/256, Ee/256, Bb), blk, 0, stream>>>(
        awb, xbT, z, altb, Ee, Cc, 0, sBCE, sBCE, 1.f);

    // 5) P[b][c][k] = (1/sqrt(C)) * sum_e y[c,e] z[k,e]       M=C,N=C,K=E
    k_gemm256<0, 0><<<dim3(Cc/256, Cc/256, Bb), blk, 0, stream>>>(
        y, z, P, nullptr, Cc, Ee, sBCE, sBCE, sBCC, 0.022097086912079608f);

    // 6) softmax rows of P (in place)
    k_softmax<<<Bb * Cc, 256, 0, stream>>>(P);

    // 7) out[b][c][e] = sum_k P[c,k] vxT[e,k] -> fp32         M=C,N=E,K=C
    k_gemm256<0, 1><<<dim3(Cc/256, Ee/256, Bb), blk, 0, stream>>>(
        P, vxT, out, nullptr, Ee, Cc, sBCC, sBCE, sBCE, 1.f);
}